// Round 17
// baseline (74.086 us; speedup 1.0000x reference)
//
#include <hip/hip_runtime.h>
#include <hip/hip_bf16.h>

typedef __bf16 bf16x8 __attribute__((ext_vector_type(8)));
typedef __bf16 bf16x4 __attribute__((ext_vector_type(4)));
typedef float  f32x4  __attribute__((ext_vector_type(4)));

#define NB  8
#define SEQ 2048
#define DM  1024
#define HD  64

#define WAITV5 asm volatile("s_waitcnt vmcnt(5)" ::: "memory")
#define WAITV0 asm volatile("s_waitcnt vmcnt(0)" ::: "memory")

__device__ __forceinline__ void gll16(const void* g, void* l) {
    __builtin_amdgcn_global_load_lds(
        (const __attribute__((address_space(1))) unsigned int*)g,
        (__attribute__((address_space(3))) unsigned int*)l, 16, 0, 0);
}

// ---------------- kernel 0: W (3 x [64,1024] f32) -> packed bf16 [192][1024]
__global__ void k_convw(const float* __restrict__ Wq, const float* __restrict__ Wk,
                        const float* __restrict__ Wv, __bf16* __restrict__ Wb) {
    int idx = blockIdx.x * blockDim.x + threadIdx.x;
    int e = idx * 4;
    const float* src;
    if (e < 65536)       src = Wq + e;
    else if (e < 131072) src = Wk + (e - 65536);
    else                 src = Wv + (e - 131072);
    float4 v = *reinterpret_cast<const float4*>(src);
    bf16x4 o;
    o[0] = (__bf16)v.x; o[1] = (__bf16)v.y; o[2] = (__bf16)v.z; o[3] = (__bf16)v.w;
    *reinterpret_cast<bf16x4*>(Wb + e) = o;
}

// ---------------- kernel 1: QKV projection v7 (r13, best measured ~20us warm).
__launch_bounds__(512, 4)
__global__ void k_proj(const float* __restrict__ X, const __bf16* __restrict__ Wb,
                       __bf16* __restrict__ Qb, __bf16* __restrict__ Kb,
                       __bf16* __restrict__ Vt) {
    __shared__ __align__(16) float  Xs[2][4096];    // 2 x 16KB (64 rows x 64 f32)
    __shared__ __align__(16) __bf16 Ws[2][12288];   // 2 x 24KB (192 rows x 64 bf16)
    const int tid = threadIdx.x;
    const int w = tid >> 6, l = tid & 63;
    const int lr = l & 15, lg = l >> 4;
    const int wm = w >> 2, wn = w & 3;
    const int m0 = blockIdx.x * 64;

    const float* xsrc[2];
    #pragma unroll
    for (int j = 0; j < 2; ++j) {
        int u = w * 128 + j * 64 + l;
        int r_ = u >> 4, c_ = u & 15;
        xsrc[j] = X + (size_t)(m0 + r_) * DM + (c_ ^ (r_ & 15)) * 4;
    }
    const __bf16* wsrc[3];
    #pragma unroll
    for (int j = 0; j < 3; ++j) {
        int u = w * 192 + j * 64 + l;
        int r_ = u >> 3, c_ = u & 7;
        wsrc[j] = Wb + (size_t)r_ * DM + (c_ ^ (r_ & 7)) * 8;
    }

    f32x4 acc[2][3];
    #pragma unroll
    for (int mt = 0; mt < 2; ++mt)
        #pragma unroll
        for (int ct = 0; ct < 3; ++ct)
            acc[mt][ct] = f32x4{0.f, 0.f, 0.f, 0.f};

    int abase[2], bbase[3];
    #pragma unroll
    for (int mt = 0; mt < 2; ++mt) abase[mt] = (wm * 32 + mt * 16 + lr) * 64;
    #pragma unroll
    for (int ct = 0; ct < 3; ++ct) bbase[ct] = ((wn * 3 + ct) * 16 + lr) * 64;

    #pragma unroll
    for (int j = 0; j < 2; ++j) gll16(xsrc[j], &Xs[0][w * 512 + j * 256]);
    #pragma unroll
    for (int j = 0; j < 3; ++j) gll16(wsrc[j], &Ws[0][w * 1536 + j * 512]);

    #pragma unroll
    for (int t = 0; t < 16; ++t) {
        const int cur = t & 1;
        __builtin_amdgcn_s_barrier();
        if (t + 1 < 16) {
            #pragma unroll
            for (int j = 0; j < 2; ++j)
                gll16(xsrc[j] + (size_t)(t + 1) * 64, &Xs[cur ^ 1][w * 512 + j * 256]);
            #pragma unroll
            for (int j = 0; j < 3; ++j)
                gll16(wsrc[j] + (size_t)(t + 1) * 64, &Ws[cur ^ 1][w * 1536 + j * 512]);
            WAITV5;
        } else {
            WAITV0;
        }
        const float*  Xp = &Xs[cur][0];
        const __bf16* Wp = &Ws[cur][0];
        #pragma unroll
        for (int ks = 0; ks < 2; ++ks) {
            bf16x8 af[2];
            #pragma unroll
            for (int mt = 0; mt < 2; ++mt) {
                f32x4 a0 = *reinterpret_cast<const f32x4*>(Xp + abase[mt] + ((ks * 8 + lg * 2)     ^ lr) * 4);
                f32x4 a1 = *reinterpret_cast<const f32x4*>(Xp + abase[mt] + ((ks * 8 + lg * 2 + 1) ^ lr) * 4);
                #pragma unroll
                for (int j = 0; j < 4; ++j) { af[mt][j] = (__bf16)a0[j]; af[mt][4 + j] = (__bf16)a1[j]; }
            }
            #pragma unroll
            for (int ct = 0; ct < 3; ++ct) {
                bf16x8 bf = *reinterpret_cast<const bf16x8*>(
                    Wp + bbase[ct] + (((ks * 4 + lg) ^ (lr & 7)) * 8));
                #pragma unroll
                for (int mt = 0; mt < 2; ++mt)
                    acc[mt][ct] = __builtin_amdgcn_mfma_f32_16x16x32_bf16(
                        af[mt], bf, acc[mt][ct], 0, 0, 0);
            }
        }
    }

    #pragma unroll
    for (int mt = 0; mt < 2; ++mt) {
        const int rowbase = m0 + wm * 32 + mt * 16 + lg * 4;
        #pragma unroll
        for (int ct = 0; ct < 3; ++ct) {
            const int ntile = wn * 3 + ct;
            const int mtx = ntile >> 2;
            const int d = (ntile & 3) * 16 + lr;
            if (mtx == 0) {
                #pragma unroll
                for (int r = 0; r < 4; ++r)
                    Qb[(size_t)(rowbase + r) * HD + d] = (__bf16)(acc[mt][ct][r] * 0.18033688f);
            } else if (mtx == 1) {
                #pragma unroll
                for (int r = 0; r < 4; ++r)
                    Kb[(size_t)(rowbase + r) * HD + d] = (__bf16)acc[mt][ct][r];
            } else {
                int bb = rowbase >> 11;
                int s0 = rowbase & 2047;
                bf16x4 vv;
                #pragma unroll
                for (int r = 0; r < 4; ++r) vv[r] = (__bf16)acc[mt][ct][r];
                *reinterpret_cast<bf16x4*>(Vt + ((size_t)bb * HD + d) * SEQ + s0) = vv;
            }
        }
    }
}

// ---------------- kernel 2: split-K causal flash attention (r13, unchanged).
// MEASUREMENT ROUND: launched TWICE; Δtotal vs r13's 55.0us = attn time.
__launch_bounds__(512)
__global__ void k_attn(const __bf16* __restrict__ Qb, const __bf16* __restrict__ Kb,
                       const __bf16* __restrict__ Vt, __bf16* __restrict__ Opart,
                       float* __restrict__ ML, int T, int NC) {
    const int bid = blockIdx.x;
    const int b = bid / (16 * NC);
    const int rem = bid - b * 16 * NC;
    const int qt2 = rem / NC;
    const int c = rem - qt2 * NC;
    const int kmax = 2 * qt2 + 1;
    if (c * T > kmax) return;
    const int kt0 = c * T;
    const int nt = min(T, kmax + 1 - kt0);
    const int q0 = qt2 * 128;

    __shared__ __align__(16) __bf16 Ks[64][72];
    __shared__ __align__(16) __bf16 Vs[64][72];    // [d][key]
    __shared__ __align__(16) __bf16 Ps[128][72];
    const int tid = threadIdx.x;
    const int w = tid >> 6, l = tid & 63;
    const int lr = l & 15, lg = l >> 4;
    const __bf16* Qp = Qb + (size_t)b * SEQ * HD;
    const __bf16* Kp = Kb + (size_t)b * SEQ * HD;
    const __bf16* Vp = Vt + (size_t)b * HD * SEQ;

    const int srow = tid >> 3, sc8 = (tid & 7) * 8;
    const int myq = q0 + 16 * w + lr;

    bf16x8 qa[2];
    #pragma unroll
    for (int ks = 0; ks < 2; ++ks)
        qa[ks] = *reinterpret_cast<const bf16x8*>(
            Qp + (size_t)myq * HD + ks * 32 + lg * 8);

    bf16x8 kpre, vpre;
    {
        const int k0 = kt0 * 64;
        kpre = *reinterpret_cast<const bf16x8*>(Kp + (size_t)(k0 + srow) * HD + sc8);
        vpre = *reinterpret_cast<const bf16x8*>(Vp + (size_t)srow * SEQ + k0 + sc8);
    }

    f32x4 oacc[4];
    #pragma unroll
    for (int r = 0; r < 4; ++r) oacc[r] = f32x4{0.f, 0.f, 0.f, 0.f};
    float m = -1e30f, lsum = 0.f;

    for (int it = 0; it < nt; ++it) {
        const int kt = kt0 + it;
        const int k0 = kt * 64;
        __syncthreads();
        *reinterpret_cast<bf16x8*>(&Ks[srow][sc8]) = kpre;
        *reinterpret_cast<bf16x8*>(&Vs[srow][sc8]) = vpre;
        __syncthreads();
        if (it + 1 < nt) {
            const int k0n = k0 + 64;
            kpre = *reinterpret_cast<const bf16x8*>(Kp + (size_t)(k0n + srow) * HD + sc8);
            vpre = *reinterpret_cast<const bf16x8*>(Vp + (size_t)srow * SEQ + k0n + sc8);
        }

        if (k0 > q0 + 16 * w + 15) continue;

        f32x4 sacc[4];
        #pragma unroll
        for (int t = 0; t < 4; ++t) sacc[t] = f32x4{0.f, 0.f, 0.f, 0.f};
        #pragma unroll
        for (int ks = 0; ks < 2; ++ks) {
            #pragma unroll
            for (int t = 0; t < 4; ++t) {
                bf16x8 kf = *reinterpret_cast<const bf16x8*>(&Ks[16 * t + lr][ks * 32 + lg * 8]);
                sacc[t] = __builtin_amdgcn_mfma_f32_16x16x32_bf16(kf, qa[ks], sacc[t], 0, 0, 0);
            }
        }

        float pmax = -1e30f;
        if (k0 + 63 > q0 + 16 * w) {
            #pragma unroll
            for (int t = 0; t < 4; ++t)
                #pragma unroll
                for (int r = 0; r < 4; ++r) {
                    float v = sacc[t][r];
                    if ((k0 + 16 * t + lg * 4 + r) > myq) v = -1e30f;
                    sacc[t][r] = v;
                    pmax = fmaxf(pmax, v);
                }
        } else {
            #pragma unroll
            for (int t = 0; t < 4; ++t)
                #pragma unroll
                for (int r = 0; r < 4; ++r) pmax = fmaxf(pmax, sacc[t][r]);
        }
        pmax = fmaxf(pmax, __shfl_xor(pmax, 16));
        pmax = fmaxf(pmax, __shfl_xor(pmax, 32));

        if (!__all(pmax <= m + 12.f)) {
            float mnew = fmaxf(m, pmax);
            float fsc = exp2f(m - mnew);
            m = mnew;
            lsum *= fsc;
            #pragma unroll
            for (int r = 0; r < 4; ++r) {
                float fq = __shfl(fsc, (l & 48) + lg * 4 + r);
                #pragma unroll
                for (int t2 = 0; t2 < 4; ++t2) oacc[t2][r] *= fq;
            }
        }

        float rs = 0.f;
        #pragma unroll
        for (int t = 0; t < 4; ++t)
            #pragma unroll
            for (int r = 0; r < 4; ++r) {
                float p = exp2f(sacc[t][r] - m);
                sacc[t][r] = p;
                rs += p;
            }
        rs += __shfl_xor(rs, 16);
        rs += __shfl_xor(rs, 32);
        lsum += rs;

        #pragma unroll
        for (int t = 0; t < 4; ++t) {
            bf16x4 pv;
            #pragma unroll
            for (int r = 0; r < 4; ++r) pv[r] = (__bf16)sacc[t][r];
            *reinterpret_cast<bf16x4*>(&Ps[16 * w + lr][16 * t + lg * 4]) = pv;
        }

        #pragma unroll
        for (int ks = 0; ks < 2; ++ks) {
            bf16x8 pa = *reinterpret_cast<const bf16x8*>(&Ps[16 * w + lr][ks * 32 + lg * 8]);
            #pragma unroll
            for (int t2 = 0; t2 < 4; ++t2) {
                bf16x8 vb = *reinterpret_cast<const bf16x8*>(&Vs[16 * t2 + lr][ks * 32 + lg * 8]);
                oacc[t2] = __builtin_amdgcn_mfma_f32_16x16x32_bf16(pa, vb, oacc[t2], 0, 0, 0);
            }
        }
    }

    const size_t slot = (size_t)bid;
    __bf16* op = Opart + slot * 8192;
    #pragma unroll
    for (int t2 = 0; t2 < 4; ++t2)
        #pragma unroll
        for (int r = 0; r < 4; ++r)
            op[(16 * w + lg * 4 + r) * 64 + 16 * t2 + lr] = (__bf16)oacc[t2][r];
    if (lg == 0) {
        float* ml = ML + slot * 256;
        int row = 16 * w + lr;
        ml[row * 2]     = m;
        ml[row * 2 + 1] = lsum;
    }
}

// ---------------- kernel 3: merge partial chunks -> Out [B][S][64] f32
__launch_bounds__(512)
__global__ void k_merge(const __bf16* __restrict__ Opart, const float* __restrict__ ML,
                        float* __restrict__ Out, int T, int NC) {
    const int bq2 = blockIdx.x >> 1;
    const int half = blockIdx.x & 1;
    const int qt2 = bq2 & 15;
    const int nc = (2 * qt2 + 1) / T + 1;
    const int tid = threadIdx.x;
    const int row = tid >> 2;
    const int cg = (tid & 3) * 8 + half * 32;
    const int base = bq2 * NC;

    float M = -1e30f;
    for (int c = 0; c < nc; ++c)
        M = fmaxf(M, ML[(size_t)(base + c) * 256 + row * 2]);

    float L = 0.f;
    f32x4 a0{0,0,0,0}, a1{0,0,0,0};
    for (int c = 0; c < nc; ++c) {
        const float* ml = ML + (size_t)(base + c) * 256 + row * 2;
        float wgt = exp2f(ml[0] - M);
        L += ml[1] * wgt;
        bf16x8 v = *reinterpret_cast<const bf16x8*>(
            Opart + (size_t)(base + c) * 8192 + row * 64 + cg);
        #pragma unroll
        for (int j = 0; j < 4; ++j) {
            a0[j] += wgt * (float)v[j];
            a1[j] += wgt * (float)v[4 + j];
        }
    }
    float inv = 1.f / L;
    #pragma unroll
    for (int j = 0; j < 4; ++j) { a0[j] *= inv; a1[j] *= inv; }
    float* o = Out + ((size_t)bq2 * 128 + row) * 64 + cg;
    *reinterpret_cast<f32x4*>(o)     = a0;
    *reinterpret_cast<f32x4*>(o + 4) = a1;
}

extern "C" void kernel_launch(void* const* d_in, const int* in_sizes, int n_in,
                              void* d_out, int out_size, void* d_ws, size_t ws_size,
                              hipStream_t stream) {
    const float* x  = (const float*)d_in[0];
    const float* wq = (const float*)d_in[1];
    const float* wk = (const float*)d_in[2];
    const float* wv = (const float*)d_in[3];
    char* ws = (char*)d_ws;
    __bf16* Wb = (__bf16*)ws;
    __bf16* Qb = (__bf16*)(ws + 524288);
    __bf16* Kb = (__bf16*)(ws + 524288 + 2097152);
    __bf16* Vt = (__bf16*)(ws + 524288 + 2 * 2097152);
    const size_t base = 524288 + 3 * 2097152;
    float* out = (float*)d_out;

    int NC = (ws_size >= base + (size_t)(8 * 16 * 4) * 17408) ? 4 : 2;
    int T = 32 / NC;
    const int slots = 8 * 16 * NC;
    float*  ML    = (float*)(ws + base);
    __bf16* Opart = (__bf16*)(ws + base + (size_t)slots * 1024);

    hipLaunchKernelGGL(k_convw, dim3(192), dim3(256), 0, stream, wq, wk, wv, Wb);
    hipLaunchKernelGGL(k_proj,  dim3(256), dim3(512), 0, stream, x, Wb, Qb, Kb, Vt);
    // MEASUREMENT: k_attn launched twice (idempotent — identical outputs).
    // attn_time = total(this round) - 55.0us (r13 baseline).
    hipLaunchKernelGGL(k_attn,  dim3(8 * 16 * NC), dim3(512), 0, stream,
                       Qb, Kb, Vt, Opart, ML, T, NC);
    hipLaunchKernelGGL(k_attn,  dim3(8 * 16 * NC), dim3(512), 0, stream,
                       Qb, Kb, Vt, Opart, ML, T, NC);
    hipLaunchKernelGGL(k_merge, dim3(256), dim3(512), 0, stream, Opart, ML, out, T, NC);
}

// Round 18
// 54.449 us; speedup vs baseline: 1.3607x; 1.3607x over previous
//
#include <hip/hip_runtime.h>
#include <hip/hip_bf16.h>

typedef __bf16 bf16x8 __attribute__((ext_vector_type(8)));
typedef __bf16 bf16x4 __attribute__((ext_vector_type(4)));
typedef float  f32x4  __attribute__((ext_vector_type(4)));

#define NB  8
#define SEQ 2048
#define DM  1024
#define HD  64

#define WAITV5 asm volatile("s_waitcnt vmcnt(5)" ::: "memory")
#define WAITV0 asm volatile("s_waitcnt vmcnt(0)" ::: "memory")

__device__ __forceinline__ void gll16(const void* g, void* l) {
    __builtin_amdgcn_global_load_lds(
        (const __attribute__((address_space(1))) unsigned int*)g,
        (__attribute__((address_space(3))) unsigned int*)l, 16, 0, 0);
}

// ---------------- kernel 0: W (3 x [64,1024] f32) -> packed bf16 [192][1024]
__global__ void k_convw(const float* __restrict__ Wq, const float* __restrict__ Wk,
                        const float* __restrict__ Wv, __bf16* __restrict__ Wb) {
    int idx = blockIdx.x * blockDim.x + threadIdx.x;
    int e = idx * 4;
    const float* src;
    if (e < 65536)       src = Wq + e;
    else if (e < 131072) src = Wk + (e - 65536);
    else                 src = Wv + (e - 131072);
    float4 v = *reinterpret_cast<const float4*>(src);
    bf16x4 o;
    o[0] = (__bf16)v.x; o[1] = (__bf16)v.y; o[2] = (__bf16)v.z; o[3] = (__bf16)v.w;
    *reinterpret_cast<bf16x4*>(Wb + e) = o;
}

// ---------------- kernel 1: QKV projection v7 (r13, ~20us measured — unchanged).
__launch_bounds__(512, 4)
__global__ void k_proj(const float* __restrict__ X, const __bf16* __restrict__ Wb,
                       __bf16* __restrict__ Qb, __bf16* __restrict__ Kb,
                       __bf16* __restrict__ Vt) {
    __shared__ __align__(16) float  Xs[2][4096];
    __shared__ __align__(16) __bf16 Ws[2][12288];
    const int tid = threadIdx.x;
    const int w = tid >> 6, l = tid & 63;
    const int lr = l & 15, lg = l >> 4;
    const int wm = w >> 2, wn = w & 3;
    const int m0 = blockIdx.x * 64;

    const float* xsrc[2];
    #pragma unroll
    for (int j = 0; j < 2; ++j) {
        int u = w * 128 + j * 64 + l;
        int r_ = u >> 4, c_ = u & 15;
        xsrc[j] = X + (size_t)(m0 + r_) * DM + (c_ ^ (r_ & 15)) * 4;
    }
    const __bf16* wsrc[3];
    #pragma unroll
    for (int j = 0; j < 3; ++j) {
        int u = w * 192 + j * 64 + l;
        int r_ = u >> 3, c_ = u & 7;
        wsrc[j] = Wb + (size_t)r_ * DM + (c_ ^ (r_ & 7)) * 8;
    }

    f32x4 acc[2][3];
    #pragma unroll
    for (int mt = 0; mt < 2; ++mt)
        #pragma unroll
        for (int ct = 0; ct < 3; ++ct)
            acc[mt][ct] = f32x4{0.f, 0.f, 0.f, 0.f};

    int abase[2], bbase[3];
    #pragma unroll
    for (int mt = 0; mt < 2; ++mt) abase[mt] = (wm * 32 + mt * 16 + lr) * 64;
    #pragma unroll
    for (int ct = 0; ct < 3; ++ct) bbase[ct] = ((wn * 3 + ct) * 16 + lr) * 64;

    #pragma unroll
    for (int j = 0; j < 2; ++j) gll16(xsrc[j], &Xs[0][w * 512 + j * 256]);
    #pragma unroll
    for (int j = 0; j < 3; ++j) gll16(wsrc[j], &Ws[0][w * 1536 + j * 512]);

    #pragma unroll
    for (int t = 0; t < 16; ++t) {
        const int cur = t & 1;
        __builtin_amdgcn_s_barrier();
        if (t + 1 < 16) {
            #pragma unroll
            for (int j = 0; j < 2; ++j)
                gll16(xsrc[j] + (size_t)(t + 1) * 64, &Xs[cur ^ 1][w * 512 + j * 256]);
            #pragma unroll
            for (int j = 0; j < 3; ++j)
                gll16(wsrc[j] + (size_t)(t + 1) * 64, &Ws[cur ^ 1][w * 1536 + j * 512]);
            WAITV5;
        } else {
            WAITV0;
        }
        const float*  Xp = &Xs[cur][0];
        const __bf16* Wp = &Ws[cur][0];
        #pragma unroll
        for (int ks = 0; ks < 2; ++ks) {
            bf16x8 af[2];
            #pragma unroll
            for (int mt = 0; mt < 2; ++mt) {
                f32x4 a0 = *reinterpret_cast<const f32x4*>(Xp + abase[mt] + ((ks * 8 + lg * 2)     ^ lr) * 4);
                f32x4 a1 = *reinterpret_cast<const f32x4*>(Xp + abase[mt] + ((ks * 8 + lg * 2 + 1) ^ lr) * 4);
                #pragma unroll
                for (int j = 0; j < 4; ++j) { af[mt][j] = (__bf16)a0[j]; af[mt][4 + j] = (__bf16)a1[j]; }
            }
            #pragma unroll
            for (int ct = 0; ct < 3; ++ct) {
                bf16x8 bf = *reinterpret_cast<const bf16x8*>(
                    Wp + bbase[ct] + (((ks * 4 + lg) ^ (lr & 7)) * 8));
                #pragma unroll
                for (int mt = 0; mt < 2; ++mt)
                    acc[mt][ct] = __builtin_amdgcn_mfma_f32_16x16x32_bf16(
                        af[mt], bf, acc[mt][ct], 0, 0, 0);
            }
        }
    }

    #pragma unroll
    for (int mt = 0; mt < 2; ++mt) {
        const int rowbase = m0 + wm * 32 + mt * 16 + lg * 4;
        #pragma unroll
        for (int ct = 0; ct < 3; ++ct) {
            const int ntile = wn * 3 + ct;
            const int mtx = ntile >> 2;
            const int d = (ntile & 3) * 16 + lr;
            if (mtx == 0) {
                #pragma unroll
                for (int r = 0; r < 4; ++r)
                    Qb[(size_t)(rowbase + r) * HD + d] = (__bf16)(acc[mt][ct][r] * 0.18033688f);
            } else if (mtx == 1) {
                #pragma unroll
                for (int r = 0; r < 4; ++r)
                    Kb[(size_t)(rowbase + r) * HD + d] = (__bf16)acc[mt][ct][r];
            } else {
                int bb = rowbase >> 11;
                int s0 = rowbase & 2047;
                bf16x4 vv;
                #pragma unroll
                for (int r = 0; r < 4; ++r) vv[r] = (__bf16)acc[mt][ct][r];
                *reinterpret_cast<bf16x4*>(Vt + ((size_t)bb * HD + d) * SEQ + s0) = vv;
            }
        }
    }
}

// ---------------- kernel 2: split-K causal flash attention, KVBLK=128.
// Halves steps/barriers/softmax-overhead vs KVBLK=64 (attn measured 19.1us
// at r13; per-step fixed costs were ~half of it). Diagonal 128-tile is fully
// mask-computed (~13% extra MFMA, accepted). T counts 128-key tiles.
__launch_bounds__(512)
__global__ void k_attn(const __bf16* __restrict__ Qb, const __bf16* __restrict__ Kb,
                       const __bf16* __restrict__ Vt, __bf16* __restrict__ Opart,
                       float* __restrict__ ML, int T, int NC) {
    const int bid = blockIdx.x;
    const int b = bid / (16 * NC);
    const int rem = bid - b * 16 * NC;
    const int qt2 = rem / NC;
    const int c = rem - qt2 * NC;
    if (c * T > qt2) return;                  // k-tiles run 0..qt2 (128-units)
    const int kt0 = c * T;
    const int nt = min(T, qt2 + 1 - kt0);
    const int q0 = qt2 * 128;

    __shared__ __align__(16) __bf16 Ks[128][72];
    __shared__ __align__(16) __bf16 Vs[64][136];   // [d][key 0..127]
    __shared__ __align__(16) __bf16 Ps[128][136];
    const int tid = threadIdx.x;
    const int w = tid >> 6, l = tid & 63;
    const int lr = l & 15, lg = l >> 4;
    const __bf16* Qp = Qb + (size_t)b * SEQ * HD;
    const __bf16* Kp = Kb + (size_t)b * SEQ * HD;
    const __bf16* Vp = Vt + (size_t)b * HD * SEQ;

    // staging coords: 1024 16B-units per tile for each of K and V, 2/thread
    const int krow0 = tid >> 3,  kcu0 = tid & 7;          // K unit 0
    const int krow1 = (tid + 512) >> 3, kcu1 = tid & 7;   // K unit 1 (+64 rows)
    const int vrow0 = tid >> 4,  vcu0 = tid & 15;         // V unit 0
    const int vrow1 = (tid + 512) >> 4, vcu1 = tid & 15;  // V unit 1 (+32 rows)
    const int myq = q0 + 16 * w + lr;

    bf16x8 qa[2];
    #pragma unroll
    for (int ks = 0; ks < 2; ++ks)
        qa[ks] = *reinterpret_cast<const bf16x8*>(
            Qp + (size_t)myq * HD + ks * 32 + lg * 8);

    bf16x8 kpre[2], vpre[2];
    {
        const int k0 = kt0 * 128;
        kpre[0] = *reinterpret_cast<const bf16x8*>(Kp + (size_t)(k0 + krow0) * HD + kcu0 * 8);
        kpre[1] = *reinterpret_cast<const bf16x8*>(Kp + (size_t)(k0 + krow1) * HD + kcu1 * 8);
        vpre[0] = *reinterpret_cast<const bf16x8*>(Vp + (size_t)vrow0 * SEQ + k0 + vcu0 * 8);
        vpre[1] = *reinterpret_cast<const bf16x8*>(Vp + (size_t)vrow1 * SEQ + k0 + vcu1 * 8);
    }

    f32x4 oacc[4];
    #pragma unroll
    for (int r = 0; r < 4; ++r) oacc[r] = f32x4{0.f, 0.f, 0.f, 0.f};
    float m = -1e30f, lsum = 0.f;

    for (int it = 0; it < nt; ++it) {
        const int kt = kt0 + it;
        const int k0 = kt * 128;
        __syncthreads();
        *reinterpret_cast<bf16x8*>(&Ks[krow0][kcu0 * 8]) = kpre[0];
        *reinterpret_cast<bf16x8*>(&Ks[krow1][kcu1 * 8]) = kpre[1];
        *reinterpret_cast<bf16x8*>(&Vs[vrow0][vcu0 * 8]) = vpre[0];
        *reinterpret_cast<bf16x8*>(&Vs[vrow1][vcu1 * 8]) = vpre[1];
        __syncthreads();
        if (it + 1 < nt) {
            const int k0n = k0 + 128;
            kpre[0] = *reinterpret_cast<const bf16x8*>(Kp + (size_t)(k0n + krow0) * HD + kcu0 * 8);
            kpre[1] = *reinterpret_cast<const bf16x8*>(Kp + (size_t)(k0n + krow1) * HD + kcu1 * 8);
            vpre[0] = *reinterpret_cast<const bf16x8*>(Vp + (size_t)vrow0 * SEQ + k0n + vcu0 * 8);
            vpre[1] = *reinterpret_cast<const bf16x8*>(Vp + (size_t)vrow1 * SEQ + k0n + vcu1 * 8);
        }

        // S^T: sacc[t][r] = S[key = k0+16t+lg*4+r][query = myq], t = 0..7
        f32x4 sacc[8];
        #pragma unroll
        for (int t = 0; t < 8; ++t) sacc[t] = f32x4{0.f, 0.f, 0.f, 0.f};
        #pragma unroll
        for (int ks = 0; ks < 2; ++ks) {
            #pragma unroll
            for (int t = 0; t < 8; ++t) {
                bf16x8 kf = *reinterpret_cast<const bf16x8*>(&Ks[16 * t + lr][ks * 32 + lg * 8]);
                sacc[t] = __builtin_amdgcn_mfma_f32_16x16x32_bf16(kf, qa[ks], sacc[t], 0, 0, 0);
            }
        }

        float pmax = -1e30f;
        if (kt == qt2) {   // diagonal tile: mask keys > myq
            #pragma unroll
            for (int t = 0; t < 8; ++t)
                #pragma unroll
                for (int r = 0; r < 4; ++r) {
                    float v = sacc[t][r];
                    if ((k0 + 16 * t + lg * 4 + r) > myq) v = -1e30f;
                    sacc[t][r] = v;
                    pmax = fmaxf(pmax, v);
                }
        } else {
            #pragma unroll
            for (int t = 0; t < 8; ++t)
                #pragma unroll
                for (int r = 0; r < 4; ++r) pmax = fmaxf(pmax, sacc[t][r]);
        }
        pmax = fmaxf(pmax, __shfl_xor(pmax, 16));
        pmax = fmaxf(pmax, __shfl_xor(pmax, 32));

        if (!__all(pmax <= m + 12.f)) {
            float mnew = fmaxf(m, pmax);
            float fsc = exp2f(m - mnew);
            m = mnew;
            lsum *= fsc;
            #pragma unroll
            for (int r = 0; r < 4; ++r) {
                float fq = __shfl(fsc, (l & 48) + lg * 4 + r);
                #pragma unroll
                for (int t2 = 0; t2 < 4; ++t2) oacc[t2][r] *= fq;
            }
        }

        float rs = 0.f;
        #pragma unroll
        for (int t = 0; t < 8; ++t)
            #pragma unroll
            for (int r = 0; r < 4; ++r) {
                float p = exp2f(sacc[t][r] - m);
                sacc[t][r] = p;
                rs += p;
            }
        rs += __shfl_xor(rs, 16);
        rs += __shfl_xor(rs, 32);
        lsum += rs;

        #pragma unroll
        for (int t = 0; t < 8; ++t) {
            bf16x4 pv;
            #pragma unroll
            for (int r = 0; r < 4; ++r) pv[r] = (__bf16)sacc[t][r];
            *reinterpret_cast<bf16x4*>(&Ps[16 * w + lr][16 * t + lg * 4]) = pv;
        }

        #pragma unroll
        for (int ks = 0; ks < 4; ++ks) {
            bf16x8 pa = *reinterpret_cast<const bf16x8*>(&Ps[16 * w + lr][ks * 32 + lg * 8]);
            #pragma unroll
            for (int t2 = 0; t2 < 4; ++t2) {
                bf16x8 vb = *reinterpret_cast<const bf16x8*>(&Vs[16 * t2 + lr][ks * 32 + lg * 8]);
                oacc[t2] = __builtin_amdgcn_mfma_f32_16x16x32_bf16(pa, vb, oacc[t2], 0, 0, 0);
            }
        }
    }

    const size_t slot = (size_t)bid;
    __bf16* op = Opart + slot * 8192;
    #pragma unroll
    for (int t2 = 0; t2 < 4; ++t2)
        #pragma unroll
        for (int r = 0; r < 4; ++r)
            op[(16 * w + lg * 4 + r) * 64 + 16 * t2 + lr] = (__bf16)oacc[t2][r];
    if (lg == 0) {
        float* ml = ML + slot * 256;
        int row = 16 * w + lr;
        ml[row * 2]     = m;
        ml[row * 2 + 1] = lsum;
    }
}

// ---------------- kernel 3: merge partial chunks -> Out [B][S][64] f32
__launch_bounds__(512)
__global__ void k_merge(const __bf16* __restrict__ Opart, const float* __restrict__ ML,
                        float* __restrict__ Out, int T, int NC) {
    const int bq2 = blockIdx.x >> 1;
    const int half = blockIdx.x & 1;
    const int qt2 = bq2 & 15;
    const int nc = qt2 / T + 1;               // T in 128-key tiles
    const int tid = threadIdx.x;
    const int row = tid >> 2;
    const int cg = (tid & 3) * 8 + half * 32;
    const int base = bq2 * NC;

    float M = -1e30f;
    for (int c = 0; c < nc; ++c)
        M = fmaxf(M, ML[(size_t)(base + c) * 256 + row * 2]);

    float L = 0.f;
    f32x4 a0{0,0,0,0}, a1{0,0,0,0};
    for (int c = 0; c < nc; ++c) {
        const float* ml = ML + (size_t)(base + c) * 256 + row * 2;
        float wgt = exp2f(ml[0] - M);
        L += ml[1] * wgt;
        bf16x8 v = *reinterpret_cast<const bf16x8*>(
            Opart + (size_t)(base + c) * 8192 + row * 64 + cg);
        #pragma unroll
        for (int j = 0; j < 4; ++j) {
            a0[j] += wgt * (float)v[j];
            a1[j] += wgt * (float)v[4 + j];
        }
    }
    float inv = 1.f / L;
    #pragma unroll
    for (int j = 0; j < 4; ++j) { a0[j] *= inv; a1[j] *= inv; }
    float* o = Out + ((size_t)bq2 * 128 + row) * 64 + cg;
    *reinterpret_cast<f32x4*>(o)     = a0;
    *reinterpret_cast<f32x4*>(o + 4) = a1;
}

extern "C" void kernel_launch(void* const* d_in, const int* in_sizes, int n_in,
                              void* d_out, int out_size, void* d_ws, size_t ws_size,
                              hipStream_t stream) {
    const float* x  = (const float*)d_in[0];
    const float* wq = (const float*)d_in[1];
    const float* wk = (const float*)d_in[2];
    const float* wv = (const float*)d_in[3];
    char* ws = (char*)d_ws;
    __bf16* Wb = (__bf16*)ws;
    __bf16* Qb = (__bf16*)(ws + 524288);
    __bf16* Kb = (__bf16*)(ws + 524288 + 2097152);
    __bf16* Vt = (__bf16*)(ws + 524288 + 2 * 2097152);
    const size_t base = 524288 + 3 * 2097152;
    float* out = (float*)d_out;

    // NC chunks of T x 128-key tiles (16 tiles max). NC=4/T=4 matches r13's
    // slot layout (512 slots); fallback NC=2/T=8 if ws is tight.
    int NC = (ws_size >= base + (size_t)(8 * 16 * 4) * 17408) ? 4 : 2;
    int T = 16 / NC;
    const int slots = 8 * 16 * NC;
    float*  ML    = (float*)(ws + base);
    __bf16* Opart = (__bf16*)(ws + base + (size_t)slots * 1024);

    hipLaunchKernelGGL(k_convw, dim3(192), dim3(256), 0, stream, wq, wk, wv, Wb);
    hipLaunchKernelGGL(k_proj,  dim3(256), dim3(512), 0, stream, x, Wb, Qb, Kb, Vt);
    hipLaunchKernelGGL(k_attn,  dim3(8 * 16 * NC), dim3(512), 0, stream,
                       Qb, Kb, Vt, Opart, ML, T, NC);
    hipLaunchKernelGGL(k_merge, dim3(256), dim3(512), 0, stream, Opart, ML, out, T, NC);
}

// Round 19
// 51.365 us; speedup vs baseline: 1.4423x; 1.0600x over previous
//
#include <hip/hip_runtime.h>
#include <hip/hip_bf16.h>

typedef __bf16 bf16x8 __attribute__((ext_vector_type(8)));
typedef __bf16 bf16x4 __attribute__((ext_vector_type(4)));
typedef float  f32x4  __attribute__((ext_vector_type(4)));

#define NB  8
#define SEQ 2048
#define DM  1024
#define HD  64

#define WAITV4 asm volatile("s_waitcnt vmcnt(4)" ::: "memory")
#define WAITV0 asm volatile("s_waitcnt vmcnt(0)" ::: "memory")

__device__ __forceinline__ void gll16(const void* g, void* l) {
    __builtin_amdgcn_global_load_lds(
        (const __attribute__((address_space(1))) unsigned int*)g,
        (__attribute__((address_space(3))) unsigned int*)l, 16, 0, 0);
}

// ---------------- kernel 0: W (3 x [64,1024] f32) -> packed bf16 [192][1024]
__global__ void k_convw(const float* __restrict__ Wq, const float* __restrict__ Wk,
                        const float* __restrict__ Wv, __bf16* __restrict__ Wb) {
    int idx = blockIdx.x * blockDim.x + threadIdx.x;
    int e = idx * 4;
    const float* src;
    if (e < 65536)       src = Wq + e;
    else if (e < 131072) src = Wk + (e - 65536);
    else                 src = Wv + (e - 131072);
    float4 v = *reinterpret_cast<const float4*>(src);
    bf16x4 o;
    o[0] = (__bf16)v.x; o[1] = (__bf16)v.y; o[2] = (__bf16)v.z; o[3] = (__bf16)v.w;
    *reinterpret_cast<bf16x4*>(Wb + e) = o;
}

// ---------------- kernel 1: QKV projection — r10's kernel VERBATIM.
// M=32, 512 thr (8 waves = 2M x 4N), grid 512 -> 2 independent blocks/CU
// (64 KB LDS). All-gll ring-2, counted vmcnt(4). Measured 2.8us faster than
// the M=64/grid-256 v7 (r10 vs r16 A/B at identical NC). Qb prescaled
// 0.125*log2(e) for exp2-domain attention.
__launch_bounds__(512, 4)
__global__ void k_proj(const float* __restrict__ X, const __bf16* __restrict__ Wb,
                       __bf16* __restrict__ Qb, __bf16* __restrict__ Kb,
                       __bf16* __restrict__ Vt) {
    __shared__ __align__(16) float  Xs[2][2048];    // 2 x 8KB  (32 rows x 64 f32)
    __shared__ __align__(16) __bf16 Ws[2][12288];   // 2 x 24KB (192 rows x 64 bf16)
    const int tid = threadIdx.x;
    const int w = tid >> 6, l = tid & 63;
    const int lr = l & 15, lg = l >> 4;
    const int wm = w >> 2, wn = w & 3;
    const int m0 = blockIdx.x * 32;

    const float* xsrc;
    {
        int u = w * 64 + l;
        int r_ = u >> 4, c_ = u & 15;
        xsrc = X + (size_t)(m0 + r_) * DM + (c_ ^ (r_ & 15)) * 4;
    }
    const __bf16* wsrc[3];
    #pragma unroll
    for (int j = 0; j < 3; ++j) {
        int u = w * 192 + j * 64 + l;
        int r_ = u >> 3, c_ = u & 7;
        wsrc[j] = Wb + (size_t)r_ * DM + (c_ ^ (r_ & 7)) * 8;
    }

    f32x4 acc[3];
    #pragma unroll
    for (int ct = 0; ct < 3; ++ct) acc[ct] = f32x4{0.f, 0.f, 0.f, 0.f};

    const int abase = (wm * 16 + lr) * 64;
    int bbase[3];
    #pragma unroll
    for (int ct = 0; ct < 3; ++ct) bbase[ct] = ((wn * 3 + ct) * 16 + lr) * 64;

    gll16(xsrc, &Xs[0][w * 256]);
    #pragma unroll
    for (int j = 0; j < 3; ++j) gll16(wsrc[j], &Ws[0][w * 1536 + j * 512]);

    #pragma unroll
    for (int t = 0; t < 16; ++t) {
        const int cur = t & 1;
        __builtin_amdgcn_s_barrier();
        if (t + 1 < 16) {
            gll16(xsrc + (size_t)(t + 1) * 64, &Xs[cur ^ 1][w * 256]);
            #pragma unroll
            for (int j = 0; j < 3; ++j)
                gll16(wsrc[j] + (size_t)(t + 1) * 64, &Ws[cur ^ 1][w * 1536 + j * 512]);
            WAITV4;
        } else {
            WAITV0;
        }
        const float*  Xp = &Xs[cur][0];
        const __bf16* Wp = &Ws[cur][0];
        #pragma unroll
        for (int ks = 0; ks < 2; ++ks) {
            f32x4 a0 = *reinterpret_cast<const f32x4*>(Xp + abase + ((ks * 8 + lg * 2)     ^ lr) * 4);
            f32x4 a1 = *reinterpret_cast<const f32x4*>(Xp + abase + ((ks * 8 + lg * 2 + 1) ^ lr) * 4);
            bf16x8 af;
            #pragma unroll
            for (int j = 0; j < 4; ++j) { af[j] = (__bf16)a0[j]; af[4 + j] = (__bf16)a1[j]; }
            #pragma unroll
            for (int ct = 0; ct < 3; ++ct) {
                bf16x8 bf = *reinterpret_cast<const bf16x8*>(
                    Wp + bbase[ct] + (((ks * 4 + lg) ^ (lr & 7)) * 8));
                acc[ct] = __builtin_amdgcn_mfma_f32_16x16x32_bf16(af, bf, acc[ct], 0, 0, 0);
            }
        }
    }

    const int rowbase = m0 + wm * 16 + lg * 4;
    #pragma unroll
    for (int ct = 0; ct < 3; ++ct) {
        const int ntile = wn * 3 + ct;
        const int mtx = ntile >> 2;
        const int d = (ntile & 3) * 16 + lr;
        if (mtx == 0) {
            #pragma unroll
            for (int r = 0; r < 4; ++r)
                Qb[(size_t)(rowbase + r) * HD + d] = (__bf16)(acc[ct][r] * 0.18033688f);
        } else if (mtx == 1) {
            #pragma unroll
            for (int r = 0; r < 4; ++r)
                Kb[(size_t)(rowbase + r) * HD + d] = (__bf16)acc[ct][r];
        } else {
            int bb = rowbase >> 11;
            int s0 = rowbase & 2047;
            bf16x4 vv;
            #pragma unroll
            for (int r = 0; r < 4; ++r) vv[r] = (__bf16)acc[ct][r];
            *reinterpret_cast<bf16x4*>(Vt + ((size_t)bb * HD + d) * SEQ + s0) = vv;
        }
    }
}

// ---------------- kernel 2: split-K causal flash attention, KVBLK=128 (r18).
__launch_bounds__(512)
__global__ void k_attn(const __bf16* __restrict__ Qb, const __bf16* __restrict__ Kb,
                       const __bf16* __restrict__ Vt, __bf16* __restrict__ Opart,
                       float* __restrict__ ML, int T, int NC) {
    const int bid = blockIdx.x;
    const int b = bid / (16 * NC);
    const int rem = bid - b * 16 * NC;
    const int qt2 = rem / NC;
    const int c = rem - qt2 * NC;
    if (c * T > qt2) return;
    const int kt0 = c * T;
    const int nt = min(T, qt2 + 1 - kt0);
    const int q0 = qt2 * 128;

    __shared__ __align__(16) __bf16 Ks[128][72];
    __shared__ __align__(16) __bf16 Vs[64][136];   // [d][key 0..127]
    __shared__ __align__(16) __bf16 Ps[128][136];
    const int tid = threadIdx.x;
    const int w = tid >> 6, l = tid & 63;
    const int lr = l & 15, lg = l >> 4;
    const __bf16* Qp = Qb + (size_t)b * SEQ * HD;
    const __bf16* Kp = Kb + (size_t)b * SEQ * HD;
    const __bf16* Vp = Vt + (size_t)b * HD * SEQ;

    const int krow0 = tid >> 3,  kcu0 = tid & 7;
    const int krow1 = (tid + 512) >> 3, kcu1 = tid & 7;
    const int vrow0 = tid >> 4,  vcu0 = tid & 15;
    const int vrow1 = (tid + 512) >> 4, vcu1 = tid & 15;
    const int myq = q0 + 16 * w + lr;

    bf16x8 qa[2];
    #pragma unroll
    for (int ks = 0; ks < 2; ++ks)
        qa[ks] = *reinterpret_cast<const bf16x8*>(
            Qp + (size_t)myq * HD + ks * 32 + lg * 8);

    bf16x8 kpre[2], vpre[2];
    {
        const int k0 = kt0 * 128;
        kpre[0] = *reinterpret_cast<const bf16x8*>(Kp + (size_t)(k0 + krow0) * HD + kcu0 * 8);
        kpre[1] = *reinterpret_cast<const bf16x8*>(Kp + (size_t)(k0 + krow1) * HD + kcu1 * 8);
        vpre[0] = *reinterpret_cast<const bf16x8*>(Vp + (size_t)vrow0 * SEQ + k0 + vcu0 * 8);
        vpre[1] = *reinterpret_cast<const bf16x8*>(Vp + (size_t)vrow1 * SEQ + k0 + vcu1 * 8);
    }

    f32x4 oacc[4];
    #pragma unroll
    for (int r = 0; r < 4; ++r) oacc[r] = f32x4{0.f, 0.f, 0.f, 0.f};
    float m = -1e30f, lsum = 0.f;

    for (int it = 0; it < nt; ++it) {
        const int kt = kt0 + it;
        const int k0 = kt * 128;
        __syncthreads();
        *reinterpret_cast<bf16x8*>(&Ks[krow0][kcu0 * 8]) = kpre[0];
        *reinterpret_cast<bf16x8*>(&Ks[krow1][kcu1 * 8]) = kpre[1];
        *reinterpret_cast<bf16x8*>(&Vs[vrow0][vcu0 * 8]) = vpre[0];
        *reinterpret_cast<bf16x8*>(&Vs[vrow1][vcu1 * 8]) = vpre[1];
        __syncthreads();
        if (it + 1 < nt) {
            const int k0n = k0 + 128;
            kpre[0] = *reinterpret_cast<const bf16x8*>(Kp + (size_t)(k0n + krow0) * HD + kcu0 * 8);
            kpre[1] = *reinterpret_cast<const bf16x8*>(Kp + (size_t)(k0n + krow1) * HD + kcu1 * 8);
            vpre[0] = *reinterpret_cast<const bf16x8*>(Vp + (size_t)vrow0 * SEQ + k0n + vcu0 * 8);
            vpre[1] = *reinterpret_cast<const bf16x8*>(Vp + (size_t)vrow1 * SEQ + k0n + vcu1 * 8);
        }

        f32x4 sacc[8];
        #pragma unroll
        for (int t = 0; t < 8; ++t) sacc[t] = f32x4{0.f, 0.f, 0.f, 0.f};
        #pragma unroll
        for (int ks = 0; ks < 2; ++ks) {
            #pragma unroll
            for (int t = 0; t < 8; ++t) {
                bf16x8 kf = *reinterpret_cast<const bf16x8*>(&Ks[16 * t + lr][ks * 32 + lg * 8]);
                sacc[t] = __builtin_amdgcn_mfma_f32_16x16x32_bf16(kf, qa[ks], sacc[t], 0, 0, 0);
            }
        }

        float pmax = -1e30f;
        if (kt == qt2) {
            #pragma unroll
            for (int t = 0; t < 8; ++t)
                #pragma unroll
                for (int r = 0; r < 4; ++r) {
                    float v = sacc[t][r];
                    if ((k0 + 16 * t + lg * 4 + r) > myq) v = -1e30f;
                    sacc[t][r] = v;
                    pmax = fmaxf(pmax, v);
                }
        } else {
            #pragma unroll
            for (int t = 0; t < 8; ++t)
                #pragma unroll
                for (int r = 0; r < 4; ++r) pmax = fmaxf(pmax, sacc[t][r]);
        }
        pmax = fmaxf(pmax, __shfl_xor(pmax, 16));
        pmax = fmaxf(pmax, __shfl_xor(pmax, 32));

        if (!__all(pmax <= m + 12.f)) {
            float mnew = fmaxf(m, pmax);
            float fsc = exp2f(m - mnew);
            m = mnew;
            lsum *= fsc;
            #pragma unroll
            for (int r = 0; r < 4; ++r) {
                float fq = __shfl(fsc, (l & 48) + lg * 4 + r);
                #pragma unroll
                for (int t2 = 0; t2 < 4; ++t2) oacc[t2][r] *= fq;
            }
        }

        float rs = 0.f;
        #pragma unroll
        for (int t = 0; t < 8; ++t)
            #pragma unroll
            for (int r = 0; r < 4; ++r) {
                float p = exp2f(sacc[t][r] - m);
                sacc[t][r] = p;
                rs += p;
            }
        rs += __shfl_xor(rs, 16);
        rs += __shfl_xor(rs, 32);
        lsum += rs;

        #pragma unroll
        for (int t = 0; t < 8; ++t) {
            bf16x4 pv;
            #pragma unroll
            for (int r = 0; r < 4; ++r) pv[r] = (__bf16)sacc[t][r];
            *reinterpret_cast<bf16x4*>(&Ps[16 * w + lr][16 * t + lg * 4]) = pv;
        }

        #pragma unroll
        for (int ks = 0; ks < 4; ++ks) {
            bf16x8 pa = *reinterpret_cast<const bf16x8*>(&Ps[16 * w + lr][ks * 32 + lg * 8]);
            #pragma unroll
            for (int t2 = 0; t2 < 4; ++t2) {
                bf16x8 vb = *reinterpret_cast<const bf16x8*>(&Vs[16 * t2 + lr][ks * 32 + lg * 8]);
                oacc[t2] = __builtin_amdgcn_mfma_f32_16x16x32_bf16(pa, vb, oacc[t2], 0, 0, 0);
            }
        }
    }

    const size_t slot = (size_t)bid;
    __bf16* op = Opart + slot * 8192;
    #pragma unroll
    for (int t2 = 0; t2 < 4; ++t2)
        #pragma unroll
        for (int r = 0; r < 4; ++r)
            op[(16 * w + lg * 4 + r) * 64 + 16 * t2 + lr] = (__bf16)oacc[t2][r];
    if (lg == 0) {
        float* ml = ML + slot * 256;
        int row = 16 * w + lr;
        ml[row * 2]     = m;
        ml[row * 2 + 1] = lsum;
    }
}

// ---------------- kernel 3: merge partial chunks -> Out [B][S][64] f32
__launch_bounds__(512)
__global__ void k_merge(const __bf16* __restrict__ Opart, const float* __restrict__ ML,
                        float* __restrict__ Out, int T, int NC) {
    const int bq2 = blockIdx.x >> 1;
    const int half = blockIdx.x & 1;
    const int qt2 = bq2 & 15;
    const int nc = qt2 / T + 1;
    const int tid = threadIdx.x;
    const int row = tid >> 2;
    const int cg = (tid & 3) * 8 + half * 32;
    const int base = bq2 * NC;

    float M = -1e30f;
    for (int c = 0; c < nc; ++c)
        M = fmaxf(M, ML[(size_t)(base + c) * 256 + row * 2]);

    float L = 0.f;
    f32x4 a0{0,0,0,0}, a1{0,0,0,0};
    for (int c = 0; c < nc; ++c) {
        const float* ml = ML + (size_t)(base + c) * 256 + row * 2;
        float wgt = exp2f(ml[0] - M);
        L += ml[1] * wgt;
        bf16x8 v = *reinterpret_cast<const bf16x8*>(
            Opart + (size_t)(base + c) * 8192 + row * 64 + cg);
        #pragma unroll
        for (int j = 0; j < 4; ++j) {
            a0[j] += wgt * (float)v[j];
            a1[j] += wgt * (float)v[4 + j];
        }
    }
    float inv = 1.f / L;
    #pragma unroll
    for (int j = 0; j < 4; ++j) { a0[j] *= inv; a1[j] *= inv; }
    float* o = Out + ((size_t)bq2 * 128 + row) * 64 + cg;
    *reinterpret_cast<f32x4*>(o)     = a0;
    *reinterpret_cast<f32x4*>(o + 4) = a1;
}

extern "C" void kernel_launch(void* const* d_in, const int* in_sizes, int n_in,
                              void* d_out, int out_size, void* d_ws, size_t ws_size,
                              hipStream_t stream) {
    const float* x  = (const float*)d_in[0];
    const float* wq = (const float*)d_in[1];
    const float* wk = (const float*)d_in[2];
    const float* wv = (const float*)d_in[3];
    char* ws = (char*)d_ws;
    __bf16* Wb = (__bf16*)ws;
    __bf16* Qb = (__bf16*)(ws + 524288);
    __bf16* Kb = (__bf16*)(ws + 524288 + 2097152);
    __bf16* Vt = (__bf16*)(ws + 524288 + 2 * 2097152);
    const size_t base = 524288 + 3 * 2097152;
    float* out = (float*)d_out;

    int NC = (ws_size >= base + (size_t)(8 * 16 * 4) * 17408) ? 4 : 2;
    int T = 16 / NC;
    const int slots = 8 * 16 * NC;
    float*  ML    = (float*)(ws + base);
    __bf16* Opart = (__bf16*)(ws + base + (size_t)slots * 1024);

    hipLaunchKernelGGL(k_convw, dim3(192), dim3(256), 0, stream, wq, wk, wv, Wb);
    hipLaunchKernelGGL(k_proj,  dim3(512), dim3(512), 0, stream, x, Wb, Qb, Kb, Vt);
    hipLaunchKernelGGL(k_attn,  dim3(8 * 16 * NC), dim3(512), 0, stream,
                       Qb, Kb, Vt, Opart, ML, T, NC);
    hipLaunchKernelGGL(k_merge, dim3(256), dim3(512), 0, stream, Opart, ML, out, T, NC);
}